// Round 11
// baseline (593.142 us; speedup 1.0000x reference)
//
#include <hip/hip_runtime.h>
#include <stdint.h>

#define NROWS 32768
#define KC 1024
#define DM 512
#define NKPROD 33554432u   // NROWS*KC

typedef _Float16 v8h __attribute__((ext_vector_type(8)));
typedef float v4f __attribute__((ext_vector_type(4)));

// ---------------- threefry2x32 (JAX-exact, key = (0, 42)) ----------------
__device__ __forceinline__ uint32_t rotl32(uint32_t x, int d) {
  return __builtin_amdgcn_alignbit(x, x, 32 - d);   // v_alignbit_b32: 1 inst
}

// Two independent chains (x0=0), ops interleaved 2-wide; returns o0^o1.
__device__ __forceinline__ void threefry_x2(uint32_t xa, uint32_t xb,
                                            uint32_t& oa, uint32_t& ob) {
  const uint32_t ks1 = 42u, ks2 = 0x1BD11BF0u;  // ks0=0; ks2=0^42^0x1BD11BDA
  uint32_t a0 = 0u, a1 = xa + ks1;
  uint32_t b0 = 0u, b1 = xb + ks1;
#define R2(r) { a0 += a1; b0 += b1; a1 = rotl32(a1, r); b1 = rotl32(b1, r); a1 ^= a0; b1 ^= b0; }
  R2(13) R2(15) R2(26) R2(6)
  a0 += ks1; b0 += ks1; a1 += ks2 + 1u; b1 += ks2 + 1u;
  R2(17) R2(29) R2(16) R2(24)
  a0 += ks2; b0 += ks2; a1 += 2u; b1 += 2u;
  R2(13) R2(15) R2(26) R2(6)
  a1 += ks1 + 3u; b1 += ks1 + 3u;                    // a0 += ks0(0)
  R2(17) R2(29) R2(16) R2(24)
  a0 += ks1; b0 += ks1; a1 += ks2 + 4u; b1 += ks2 + 4u;
  R2(13) R2(15) R2(26) R2(6)
  a0 += ks2; b0 += ks2; a1 += 5u; b1 += 5u;
#undef R2
  oa = a0 ^ a1;
  ob = b0 ^ b1;
}

// ---------------- prep (block 0) + B split (blocks 1..64) ----------------
// idx[0..NP) = non-pad rows ascending; idx[NP..32768) = pad rows ascending.
__global__ __launch_bounds__(1024) void k_prep_b(const void* __restrict__ mv,
                                                 const float* __restrict__ B,
                                                 uint8_t* __restrict__ wm,
                                                 int* __restrict__ idx,
                                                 int* __restrict__ npp,
                                                 _Float16* __restrict__ Bh2,
                                                 _Float16* __restrict__ Bl2,
                                                 float* __restrict__ Bn) {
  if (blockIdx.x > 0) {
    // ---- codebook pre-split: one code per wave (16 waves/block, 64 blocks) ----
    int k = (blockIdx.x - 1) * 16 + (threadIdx.x >> 6);
    int l = threadIdx.x & 63;
    const float* bp = B + (size_t)k * DM + l * 8;
    float x[8];
    *(float4*)&x[0] = *(const float4*)bp;
    *(float4*)&x[4] = *(const float4*)(bp + 4);
    _Float16 h[8], lo[8];
    float s = 0.f;
#pragma unroll
    for (int i = 0; i < 8; ++i) {
      _Float16 hh = (_Float16)x[i];
      h[i] = hh; lo[i] = (_Float16)(x[i] - (float)hh);
      s = fmaf(x[i], x[i], s);
    }
    *(v8h*)&Bh2[(size_t)k * DM + l * 8] = *(v8h*)h;
    *(v8h*)&Bl2[(size_t)k * DM + l * 8] = *(v8h*)lo;
#pragma unroll
    for (int off = 32; off; off >>= 1) s += __shfl_xor(s, off, 64);
    if (l == 0) Bn[k] = s;
    return;
  }

  // ---- detect + normalize + dual ordered compaction ----
  __shared__ uint32_t sflag;
  __shared__ int scnt[1024];
  int t = threadIdx.x;
  if (t == 0) sflag = 0;
  __syncthreads();
  const uint8_t* mb = (const uint8_t*)mv;
  uint32_t f = 0;
  for (int i = t; i < NROWS; i += 1024)
    if ((i & 3) && mb[i]) f = 1;   // nonzero high byte => 1-byte bool layout
  if (f) atomicOr(&sflag, 1u);
  __syncthreads();
  bool isbool = sflag != 0;

  int r0 = t * 32;
  int cnt = 0;
  for (int i = 0; i < 32; ++i) {
    int r = r0 + i;
    bool p = isbool ? (mb[r] != 0) : (((const int*)mv)[r] != 0);
    wm[r] = p ? 1u : 0u;
    cnt += p ? 0 : 1;
  }
  scnt[t] = cnt;
  __syncthreads();
  for (int off = 1; off < 1024; off <<= 1) {
    int v = (t >= off) ? scnt[t - off] : 0;
    __syncthreads();
    scnt[t] += v;
    __syncthreads();
  }
  int NPtot = scnt[1023];
  int pos  = scnt[t] - cnt;             // non-pad exclusive prefix
  int ppos = NPtot + (r0 - pos);        // pad slots start at NPtot
  for (int i = 0; i < 32; ++i) {
    int r = r0 + i;
    bool p = isbool ? (mb[r] != 0) : (((const int*)mv)[r] != 0);
    if (!p) idx[pos++] = r; else idx[ppos++] = r;
  }
  if (t == 1023) *npp = NPtot;
}

// ---------------- GEMM (active groups) + far-pad handling (idle blocks) ----------------
// Active: logits S[idx[slot],k] = -((||x||^2+||c||^2) - 2 x.c), f16 two-term split.
// Idle (by >= ngroups): pad rows slot >= ngroups*128 -> counts row + loss.
// (qout zeroing for pad rows is done by the sampler; Bh2/Bl2 live in qout region.)
#define LDK 40   // padded BK stride in f16 (80 B, 16B-aligned)
__global__ __launch_bounds__(256) void k_gemm4(const float* __restrict__ A,
                                               const _Float16* __restrict__ Bh2,
                                               const _Float16* __restrict__ Bl2,
                                               const float* __restrict__ Bn,
                                               const int* __restrict__ idx,
                                               const int* __restrict__ npp,
                                               float* __restrict__ S,
                                               double* __restrict__ esum) {
  int NP = *npp;
  int ngroups = (NP + 127) >> 7;
  int bx = blockIdx.x & 7;           // N panel
  int by = blockIdx.x >> 3;          // M panel (compact slots)
  int tid = threadIdx.x;

  if (by >= ngroups) {
    // ----- far-pad rows: counts(c0=10) into S + loss; one row per wave -----
    int pbase = ngroups << 7;
    int pcount = NROWS - pbase;
    if (pcount <= 0) return;
    int nidle = (256 - ngroups) * 8;
    int iidx = (by - ngroups) * 8 + bx;
    int chunk = (pcount + nidle - 1) / nidle;
    int s0 = pbase + iidx * chunk;
    int s1 = s0 + chunk; if (s1 > NROWS) s1 = NROWS;
    int wid = tid >> 6, l = tid & 63;
    for (int s = s0 + wid; s < s1; s += 4) {
      int n = idx[s];
      float* so = S + (size_t)n * KC + l * 16;
      float4 z = make_float4(0.f, 0.f, 0.f, 0.f);
      *(float4*)(so)      = (l == 0) ? make_float4(10.f, 0.f, 0.f, 0.f) : z;
      *(float4*)(so + 4)  = z;
      *(float4*)(so + 8)  = z;
      *(float4*)(so + 12) = z;
      const float* xr = A + (size_t)n * DM + l * 8;
      float4 x0 = *(const float4*)xr, x1 = *(const float4*)(xr + 4);
      double ls = (double)(x0.x*x0.x) + (double)(x0.y*x0.y)
                + (double)(x0.z*x0.z) + (double)(x0.w*x0.w)
                + (double)(x1.x*x1.x) + (double)(x1.y*x1.y)
                + (double)(x1.z*x1.z) + (double)(x1.w*x1.w);
#pragma unroll
      for (int off = 32; off; off >>= 1) ls += __shfl_xor(ls, off, 64);
      if (l == 0) atomicAdd(&esum[n & 63], ls);
    }
    return;
  }

  __shared__ _Float16 Ah[128 * LDK], Al[128 * LDK];
  __shared__ _Float16 Bh[128 * LDK], Bl[128 * LDK];
  __shared__ float rs[128];
  __shared__ float cs[128];
  __shared__ float tmp[256];

  int r0 = by * 128, c0 = bx * 128;
  int wid = tid >> 6;
  int wr = wid >> 1, wc = wid & 1;   // wave sub-tile (64x64)
  int l = tid & 63;
  int lr = l & 15;
  int k8 = (l >> 4) * 8;

  int srow = tid >> 1;               // staging slot-row 0..127
  int ssub = (tid & 1) * 16;         // staging k sub-offset

  int orig = idx[r0 + srow];
  const float* ag = A + (size_t)orig * DM + ssub;
  const _Float16* bhg = Bh2 + (size_t)(c0 + srow) * DM + ssub;
  const _Float16* blg = Bl2 + (size_t)(c0 + srow) * DM + ssub;

  if (tid < 128) cs[tid] = Bn[c0 + tid];

  v4f acc[4][4];
#pragma unroll
  for (int m = 0; m < 4; ++m)
#pragma unroll
    for (int n = 0; n < 4; ++n) acc[m][n] = (v4f)0.0f;

  float sqa = 0.f;

  for (int k0 = 0; k0 < DM; k0 += 32) {
    float xa[16];
#pragma unroll
    for (int i = 0; i < 16; i += 4)
      *(float4*)&xa[i] = *(const float4*)(ag + k0 + i);
    v8h bh0 = *(const v8h*)(bhg + k0);
    v8h bh1 = *(const v8h*)(bhg + k0 + 8);
    v8h bl0 = *(const v8h*)(blg + k0);
    v8h bl1 = *(const v8h*)(blg + k0 + 8);
    _Float16 ha[16], la[16];
#pragma unroll
    for (int i = 0; i < 16; ++i) {
      float x = xa[i];
      _Float16 h = (_Float16)x;
      ha[i] = h; la[i] = (_Float16)(x - (float)h);
      sqa = fmaf(x, x, sqa);
    }
    __syncthreads();   // previous iter's frag reads done
    int wb = srow * LDK + ssub;
    *(v8h*)&Ah[wb]     = *(v8h*)&ha[0];
    *(v8h*)&Ah[wb + 8] = *(v8h*)&ha[8];
    *(v8h*)&Al[wb]     = *(v8h*)&la[0];
    *(v8h*)&Al[wb + 8] = *(v8h*)&la[8];
    *(v8h*)&Bh[wb]     = bh0;
    *(v8h*)&Bh[wb + 8] = bh1;
    *(v8h*)&Bl[wb]     = bl0;
    *(v8h*)&Bl[wb + 8] = bl1;
    __syncthreads();

    v8h fah[4], fal[4];
#pragma unroll
    for (int m = 0; m < 4; ++m) {
      int row = wr * 64 + m * 16 + lr;
      fah[m] = *(const v8h*)&Ah[row * LDK + k8];
      fal[m] = *(const v8h*)&Al[row * LDK + k8];
    }
#pragma unroll
    for (int n = 0; n < 4; ++n) {
      int col = wc * 64 + n * 16 + lr;
      v8h fbh = *(const v8h*)&Bh[col * LDK + k8];
      v8h fbl = *(const v8h*)&Bl[col * LDK + k8];
#pragma unroll
      for (int m = 0; m < 4; ++m) {
        acc[m][n] = __builtin_amdgcn_mfma_f32_16x16x32_f16(fah[m], fbh, acc[m][n], 0, 0, 0);
        acc[m][n] = __builtin_amdgcn_mfma_f32_16x16x32_f16(fah[m], fbl, acc[m][n], 0, 0, 0);
        acc[m][n] = __builtin_amdgcn_mfma_f32_16x16x32_f16(fal[m], fbh, acc[m][n], 0, 0, 0);
      }
    }
  }

  // A-row norms (pair-sum of per-thread halves)
  tmp[tid] = sqa;
  __syncthreads();
  if ((tid & 1) == 0) rs[srow] = tmp[tid] + tmp[tid + 1];
  __syncthreads();

  float cnp[4];
#pragma unroll
  for (int n = 0; n < 4; ++n) cnp[n] = cs[wc * 64 + n * 16 + lr];

#pragma unroll
  for (int m = 0; m < 4; ++m) {
    int rl = wr * 64 + m * 16 + (l >> 4) * 4;
#pragma unroll
    for (int r = 0; r < 4; ++r) {
      int org = idx[r0 + rl + r];
      float rq = rs[rl + r];
      float* sp = S + (size_t)org * KC + c0;
#pragma unroll
      for (int n = 0; n < 4; ++n) {
        int cl = wc * 64 + n * 16 + lr;
        sp[cl] = -((rq + cnp[n]) - 2.0f * acc[m][n][r]);
      }
    }
  }
}

// ---------------- sampling (non-pad) + qout-zero / tail-pad ----------------
// slot < NP: bit-identical draw stream (bits = o0^o1 of threefry(key,(0,t));
// argmax fl(log2(u)*m), m = ln2*exp(lmax-l)).
// slot >= NP: zero qout row; tail slots [NP, ngroups*128) also counts+loss.
__global__ __launch_bounds__(256, 8) void k_sample_g(
    const float* __restrict__ S, const float* __restrict__ X,
    const float* __restrict__ CW, const int* __restrict__ idx,
    const int* __restrict__ npp,
    float* __restrict__ qout, float* __restrict__ sout,
    float* __restrict__ cnt, double* __restrict__ esum) {
  int NP = *npp;
  int slot = blockIdx.x * 4 + (threadIdx.x >> 6);
  int l = threadIdx.x & 63;
  int n = idx[slot];
  int base = l * 16;

  if (slot >= NP) {
    float4 z = make_float4(0.f, 0.f, 0.f, 0.f);
    float* qo = qout + (size_t)n * DM + l * 8;
    *(float4*)qo       = z;
    *(float4*)(qo + 4) = z;
    int ngroups = (NP + 127) >> 7;
    if (slot < (ngroups << 7)) {   // tail-pad: counts + loss (gemm wrote logits here)
      float* so = sout + (size_t)n * KC + base;
      *(float4*)(so)      = (l == 0) ? make_float4(10.f, 0.f, 0.f, 0.f) : z;
      *(float4*)(so + 4)  = z;
      *(float4*)(so + 8)  = z;
      *(float4*)(so + 12) = z;
      const float* xr = X + (size_t)n * DM + l * 8;
      float4 x0 = *(const float4*)xr, x1 = *(const float4*)(xr + 4);
      double ls = (double)(x0.x*x0.x) + (double)(x0.y*x0.y)
                + (double)(x0.z*x0.z) + (double)(x0.w*x0.w)
                + (double)(x1.x*x1.x) + (double)(x1.y*x1.y)
                + (double)(x1.z*x1.z) + (double)(x1.w*x1.w);
#pragma unroll
      for (int off = 32; off; off >>= 1) ls += __shfl_xor(ls, off, 64);
      if (l == 0) atomicAdd(&esum[n & 63], ls);
    }
    return;
  }

  const float* srow = S + (size_t)n * KC + base;

  // row max (transient lg regs)
  float lmax;
  {
    float lg0[16];
#pragma unroll
    for (int j = 0; j < 16; j += 4)
      *(float4*)&lg0[j] = *(const float4*)(srow + j);
    if (l == 0) lg0[0] = -__builtin_inff();
    lmax = lg0[0];
#pragma unroll
    for (int i = 1; i < 16; ++i) lmax = fmaxf(lmax, lg0[i]);
#pragma unroll
    for (int off = 32; off; off >>= 1)
      lmax = fmaxf(lmax, __shfl_xor(lmax, off, 64));
  }

  float bv[10];
  uint32_t bi[10];
#pragma unroll
  for (int s = 0; s < 10; ++s) { bv[s] = -__builtin_inff(); bi[s] = 0xFFFFFFFFu; }

  uint32_t tb0 = (uint32_t)n * (uint32_t)KC + (uint32_t)base;
#pragma unroll 1
  for (int j = 0; j < 16; ++j) {
    float lgj = srow[j];                 // L1-hot scalar reload
    uint32_t kk = (uint32_t)(base + j);
    if (kk == 0u) lgj = -__builtin_inff();  // code 0 disallowed
    float mj = 0.69314718056f * __expf(lmax - lgj);
    uint32_t t0 = tb0 + (uint32_t)j;
#pragma unroll
    for (int sp = 0; sp < 5; ++sp) {
      uint32_t ba, bb;
      threefry_x2(t0 + (uint32_t)(2 * sp) * NKPROD,
                  t0 + (uint32_t)(2 * sp + 1) * NKPROD, ba, bb);
      float fa = __uint_as_float((ba >> 9) | 0x3F800000u) - 1.0f;
      float fb = __uint_as_float((bb >> 9) | 0x3F800000u) - 1.0f;
      float ua = fmaxf(1.17549435e-38f, fa);
      float ub = fmaxf(1.17549435e-38f, fb);
      float va = __log2f(ua) * mj;
      float vb = __log2f(ub) * mj;
      if (va > bv[2 * sp])     { bv[2 * sp] = va;     bi[2 * sp] = kk; }
      if (vb > bv[2 * sp + 1]) { bv[2 * sp + 1] = vb; bi[2 * sp + 1] = kk; }
    }
  }

  // wave argmax per draw (first-index tiebreak)
#pragma unroll
  for (int s = 0; s < 10; ++s) {
#pragma unroll
    for (int off = 32; off; off >>= 1) {
      float ov = __shfl_xor(bv[s], off, 64);
      uint32_t oi = __shfl_xor(bi[s], off, 64);
      if (ov > bv[s] || (ov == bv[s] && oi < bi[s])) { bv[s] = ov; bi[s] = oi; }
    }
  }

  // counts (transient; overwrites this row's logits)
  float* so = sout + (size_t)n * KC + base;
#pragma unroll
  for (int j4 = 0; j4 < 16; j4 += 4) {
    float c[4];
#pragma unroll
    for (int i = 0; i < 4; ++i) {
      uint32_t k = (uint32_t)(base + j4 + i);
      float cc = 0.f;
#pragma unroll
      for (int s = 0; s < 10; ++s) cc += (bi[s] == k) ? 1.f : 0.f;
      c[i] = cc;
    }
    *(float4*)(so + j4) = make_float4(c[0], c[1], c[2], c[3]);
  }

  // quantized gather (bi wave-uniform; codebook L2-hot) + ST + loss
  float q[8];
#pragma unroll
  for (int i = 0; i < 8; ++i) q[i] = 0.f;
#pragma unroll
  for (int s = 0; s < 10; ++s) {
    const float* cr = CW + (size_t)bi[s] * DM + l * 8;
    float4 g0 = *(const float4*)cr;
    float4 g1 = *(const float4*)(cr + 4);
    q[0] += g0.x; q[1] += g0.y; q[2] += g0.z; q[3] += g0.w;
    q[4] += g1.x; q[5] += g1.y; q[6] += g1.z; q[7] += g1.w;
    if (l == 0) atomicAdd(&cnt[bi[s]], 1.0f);
  }

  const float* xr = X + (size_t)n * DM + l * 8;
  float4 x0 = *(const float4*)xr, x1 = *(const float4*)(xr + 4);
  float xs[8] = {x0.x, x0.y, x0.z, x0.w, x1.x, x1.y, x1.z, x1.w};
  float st[8];
  double ls = 0.0;
#pragma unroll
  for (int j = 0; j < 8; ++j) {
    float qq = q[j] / 10.0f;
    float d = qq - xs[j];
    ls += (double)(d * d);
    st[j] = xs[j] + d;
  }
  float* qo = qout + (size_t)n * DM + l * 8;
  *(float4*)qo       = make_float4(st[0], st[1], st[2], st[3]);
  *(float4*)(qo + 4) = make_float4(st[4], st[5], st[6], st[7]);

#pragma unroll
  for (int off = 32; off; off >>= 1) ls += __shfl_xor(ls, off, 64);
  if (l == 0) atomicAdd(&esum[n & 63], ls);   // 64 striped slots
}

// ---------------- scalars: loss + perplexity ----------------
__global__ __launch_bounds__(256) void k_final(const uint8_t* __restrict__ wm,
                                               const float* __restrict__ cnt,
                                               const double* __restrict__ esum,
                                               float* __restrict__ scal) {
  __shared__ int sni[256];
  __shared__ double snd[256];
  int t = threadIdx.x;
  int np = 0;
  for (int i = t; i < NROWS; i += 256) np += wm[i];
  sni[t] = np;
  __syncthreads();
  for (int off = 128; off; off >>= 1) {
    if (t < off) sni[t] += sni[t + off];
    __syncthreads();
  }
  int npad = sni[0];
  double ss = 0.0;
  for (int k = t; k < KC; k += 256) {
    float c = (k == 0) ? (float)(npad * 10) : cnt[k];
    float p = c / 327680.0f;   // / (N * NUM_SAMPLES)
    ss += (double)(p * logf(p + 1e-10f));
  }
  snd[t] = ss;
  __syncthreads();
  for (int off = 128; off; off >>= 1) {
    if (t < off) snd[t] += snd[t + off];
    __syncthreads();
  }
  if (t == 0) {
    double es = 0.0;
    for (int i = 0; i < 64; ++i) es += esum[i];
    float num_nonpad = (float)((NROWS - npad) * DM);
    float el = (float)(*esum == *esum ? es : es) / num_nonpad;
    el = (float)es / num_nonpad;
    scal[0] = 0.25f * el;               // loss
    scal[1] = expf(-(float)snd[0]);     // perplexity
  }
}

extern "C" void kernel_launch(void* const* d_in, const int* in_sizes, int n_in,
                              void* d_out, int out_size, void* d_ws, size_t ws_size,
                              hipStream_t stream) {
  const float* X  = (const float*)d_in[0];
  const void*  M  = d_in[1];
  const float* CW = (const float*)d_in[2];
  float* out  = (float*)d_out;
  float* qout = out;                    // [0, 16777216): quantized_st (scratch until sampler)
  float* sout = out + 16777216;         // [.., 50331648): logits -> samples
  float* scal = out + 50331648;         // loss, perplexity
  // B pre-split scratch in qout region (every qout row rewritten by sampler):
  _Float16* Bh2 = (_Float16*)qout;              // 1024x512 f16
  _Float16* Bl2 = (_Float16*)(qout + 262144);
  float*    Bn  = qout + 524288;                // 1024 floats
  uint8_t* ws = (uint8_t*)d_ws;
  double*   esum = (double*)ws;         // 512 B (64 striped slots)
  int*      npp  = (int*)(ws + 512);    // 4 B
  float*    cnt  = (float*)(ws + 1024); // 4 KB (per-code totals)
  uint8_t*  wm   = ws + 16384;          // 32 KB (normalized byte mask)
  int*      idx  = (int*)(ws + 49152);  // 128 KB (nonpad [0,NP) + pad [NP,32768))
  (void)in_sizes; (void)n_in; (void)out_size; (void)ws_size;

  hipMemsetAsync(d_ws, 0, 8192, stream);                 // esum + npp + cnt
  k_prep_b<<<65, 1024, 0, stream>>>(M, CW, wm, idx, npp, Bh2, Bl2, Bn);
  k_gemm4<<<2048, 256, 0, stream>>>(X, Bh2, Bl2, Bn, idx, npp, sout, esum);
  k_sample_g<<<8192, 256, 0, stream>>>(sout, X, CW, idx, npp, qout, sout, cnt, esum);
  k_final<<<1, 256, 0, stream>>>(wm, cnt, esum, scal);
}

// Round 12
// 508.686 us; speedup vs baseline: 1.1660x; 1.1660x over previous
//
#include <hip/hip_runtime.h>
#include <stdint.h>

#define NROWS 32768
#define KC 1024
#define DM 512
#define NKPROD 33554432u   // NROWS*KC

typedef _Float16 v8h __attribute__((ext_vector_type(8)));
typedef float v4f __attribute__((ext_vector_type(4)));

// ---------------- threefry2x32 (JAX-exact, key = (0, 42)) ----------------
__device__ __forceinline__ uint32_t rotl32(uint32_t x, int d) {
  return __builtin_amdgcn_alignbit(x, x, 32 - d);   // v_alignbit_b32: 1 inst
}

// Two independent chains (x0=0), ops interleaved 2-wide; returns o0^o1.
__device__ __forceinline__ void threefry_x2(uint32_t xa, uint32_t xb,
                                            uint32_t& oa, uint32_t& ob) {
  const uint32_t ks1 = 42u, ks2 = 0x1BD11BF0u;  // ks0=0; ks2=0^42^0x1BD11BDA
  uint32_t a0 = 0u, a1 = xa + ks1;
  uint32_t b0 = 0u, b1 = xb + ks1;
#define R2(r) { a0 += a1; b0 += b1; a1 = rotl32(a1, r); b1 = rotl32(b1, r); a1 ^= a0; b1 ^= b0; }
  R2(13) R2(15) R2(26) R2(6)
  a0 += ks1; b0 += ks1; a1 += ks2 + 1u; b1 += ks2 + 1u;
  R2(17) R2(29) R2(16) R2(24)
  a0 += ks2; b0 += ks2; a1 += 2u; b1 += 2u;
  R2(13) R2(15) R2(26) R2(6)
  a1 += ks1 + 3u; b1 += ks1 + 3u;                    // a0 += ks0(0)
  R2(17) R2(29) R2(16) R2(24)
  a0 += ks1; b0 += ks1; a1 += ks2 + 4u; b1 += ks2 + 4u;
  R2(13) R2(15) R2(26) R2(6)
  a0 += ks2; b0 += ks2; a1 += 5u; b1 += 5u;
#undef R2
  oa = a0 ^ a1;
  ob = b0 ^ b1;
}

// ---------------- parallel compaction: count (+dtype detect) ----------------
__global__ __launch_bounds__(256) void k_count(const uint8_t* __restrict__ mb,
                                               uint32_t* __restrict__ flag,
                                               int* __restrict__ cntB,
                                               int* __restrict__ cntI) {
  __shared__ int sB[256], sI[256];
  int t = threadIdx.x, b = blockIdx.x;
  int T = b * 256 + t;
  uint32_t f = 0;
#pragma unroll
  for (int i = 0; i < 2; ++i) {
    int bi = T * 2 + i;
    if ((bi & 3) && mb[bi]) f = 1;   // nonzero high byte => 1-byte bool layout
  }
  if (f) atomicOr(flag, 1u);
  const int* mi = (const int*)mb;
  int r0 = b * 512 + t * 2;
  int cB = 0, cI = 0;
#pragma unroll
  for (int i = 0; i < 2; ++i) {
    int r = r0 + i;
    cB += (mb[r] == 0) ? 1 : 0;
    cI += (mi[r] == 0) ? 1 : 0;
  }
  sB[t] = cB; sI[t] = cI;
  __syncthreads();
  for (int off = 128; off; off >>= 1) {
    if (t < off) { sB[t] += sB[t + off]; sI[t] += sI[t + off]; }
    __syncthreads();
  }
  if (t == 0) { cntB[b] = sB[0]; cntI[b] = sI[0]; }
}

// ---------------- parallel compaction: scatter (order-preserving) ----------------
// idx[0..NP) = non-pad rows ascending; idx[NP..32768) = pad rows ascending.
__global__ __launch_bounds__(256) void k_scatter(const uint8_t* __restrict__ mb,
                                                 const uint32_t* __restrict__ flag,
                                                 const int* __restrict__ cntB,
                                                 const int* __restrict__ cntI,
                                                 int* __restrict__ idx,
                                                 int* __restrict__ npp) {
  __shared__ int sc[256];
  int t = threadIdx.x, b = blockIdx.x;
  bool isbool = (*flag) != 0;
  const int* mi = (const int*)mb;
  const int* cnt = isbool ? cntB : cntI;
  int pre = 0, tot = 0;
  for (int j = 0; j < 64; ++j) {
    int c = cnt[j];
    if (j < b) pre += c;
    tot += c;
  }
  int r0 = b * 512 + t * 2;
  bool np0 = isbool ? (mb[r0] == 0)     : (mi[r0] == 0);
  bool np1 = isbool ? (mb[r0 + 1] == 0) : (mi[r0 + 1] == 0);
  int my = (int)np0 + (int)np1;
  sc[t] = my;
  __syncthreads();
  for (int off = 1; off < 256; off <<= 1) {
    int v = (t >= off) ? sc[t - off] : 0;
    __syncthreads();
    sc[t] += v;
    __syncthreads();
  }
  int excl = sc[t] - my;                 // nonpad rows before this thread in block
  int npPos = pre + excl;
  int padPos = tot + (b * 512 - pre) + (t * 2 - excl);
  if (np0) idx[npPos++] = r0;     else idx[padPos++] = r0;
  if (np1) idx[npPos]   = r0 + 1; else idx[padPos]   = r0 + 1;
  if (b == 0 && t == 0) *npp = tot;
}

// ---------------- A pre-split by slot: f16 hi/lo + row norms ----------------
// Ah2/Al2 live in the qout region (rewritten by pad/sampler afterwards).
__global__ __launch_bounds__(256) void k_asplit(const float* __restrict__ A,
                                                const int* __restrict__ idx,
                                                _Float16* __restrict__ Ah2,
                                                _Float16* __restrict__ Al2,
                                                float* __restrict__ An) {
  int slot = blockIdx.x * 4 + (threadIdx.x >> 6);
  int l = threadIdx.x & 63;
  int n = idx[slot];
  const float* ap = A + (size_t)n * DM + l * 8;
  float x[8];
  *(float4*)&x[0] = *(const float4*)ap;
  *(float4*)&x[4] = *(const float4*)(ap + 4);
  _Float16 h[8], lo[8];
  float s = 0.f;
#pragma unroll
  for (int i = 0; i < 8; ++i) {
    _Float16 hh = (_Float16)x[i];
    h[i] = hh; lo[i] = (_Float16)(x[i] - (float)hh);
    s = fmaf(x[i], x[i], s);
  }
  *(v8h*)&Ah2[(size_t)slot * DM + l * 8] = *(v8h*)h;
  *(v8h*)&Al2[(size_t)slot * DM + l * 8] = *(v8h*)lo;
#pragma unroll
  for (int off = 32; off; off >>= 1) s += __shfl_xor(s, off, 64);
  if (l == 0) An[slot] = s;
}

// ---------------- B pre-split: f16 hi/lo + row norms (to ws) ----------------
__global__ __launch_bounds__(256) void k_bsplit(const float* __restrict__ B,
                                                _Float16* __restrict__ Bh2,
                                                _Float16* __restrict__ Bl2,
                                                float* __restrict__ Bn) {
  int k = blockIdx.x * 4 + (threadIdx.x >> 6);
  int l = threadIdx.x & 63;
  const float* bp = B + (size_t)k * DM + l * 8;
  float x[8];
  *(float4*)&x[0] = *(const float4*)bp;
  *(float4*)&x[4] = *(const float4*)(bp + 4);
  _Float16 h[8], lo[8];
  float s = 0.f;
#pragma unroll
  for (int i = 0; i < 8; ++i) {
    _Float16 hh = (_Float16)x[i];
    h[i] = hh; lo[i] = (_Float16)(x[i] - (float)hh);
    s = fmaf(x[i], x[i], s);
  }
  *(v8h*)&Bh2[(size_t)k * DM + l * 8] = *(v8h*)h;
  *(v8h*)&Bl2[(size_t)k * DM + l * 8] = *(v8h*)lo;
#pragma unroll
  for (int off = 32; off; off >>= 1) s += __shfl_xor(s, off, 64);
  if (l == 0) Bn[k] = s;
}

// ---------------- logits GEMM: all operands pre-split, VALU-light K-loop ----------------
#define LDK 40   // padded BK stride in f16 (80 B, 16B-aligned)
__global__ __launch_bounds__(256) void k_gemm5(const _Float16* __restrict__ Ah2,
                                               const _Float16* __restrict__ Al2,
                                               const float* __restrict__ An,
                                               const _Float16* __restrict__ Bh2,
                                               const _Float16* __restrict__ Bl2,
                                               const float* __restrict__ Bn,
                                               const int* __restrict__ idx,
                                               const int* __restrict__ npp,
                                               float* __restrict__ S) {
  int NP = *npp;
  int bx = blockIdx.x & 7;           // N panel
  int by = blockIdx.x >> 3;          // M panel (compact slots)
  int r0 = by * 128, c0 = bx * 128;
  if (r0 >= NP) return;

  __shared__ _Float16 Ah[128 * LDK], Al[128 * LDK];
  __shared__ _Float16 Bh[128 * LDK], Bl[128 * LDK];

  int tid = threadIdx.x;
  int wid = tid >> 6;
  int wr = wid >> 1, wc = wid & 1;   // wave sub-tile (64x64)
  int l = tid & 63;
  int lr = l & 15;
  int k8 = (l >> 4) * 8;

  int srow = tid >> 1;               // staging slot-row 0..127
  int ssub = (tid & 1) * 16;         // staging k sub-offset

  const _Float16* ahg = Ah2 + (size_t)(r0 + srow) * DM + ssub;
  const _Float16* alg = Al2 + (size_t)(r0 + srow) * DM + ssub;
  const _Float16* bhg = Bh2 + (size_t)(c0 + srow) * DM + ssub;
  const _Float16* blg = Bl2 + (size_t)(c0 + srow) * DM + ssub;

  v4f acc[4][4];
#pragma unroll
  for (int m = 0; m < 4; ++m)
#pragma unroll
    for (int n = 0; n < 4; ++n) acc[m][n] = (v4f)0.0f;

  for (int k0 = 0; k0 < DM; k0 += 32) {
    v8h ah0 = *(const v8h*)(ahg + k0);
    v8h ah1 = *(const v8h*)(ahg + k0 + 8);
    v8h al0 = *(const v8h*)(alg + k0);
    v8h al1 = *(const v8h*)(alg + k0 + 8);
    v8h bh0 = *(const v8h*)(bhg + k0);
    v8h bh1 = *(const v8h*)(bhg + k0 + 8);
    v8h bl0 = *(const v8h*)(blg + k0);
    v8h bl1 = *(const v8h*)(blg + k0 + 8);
    __syncthreads();   // previous iter's frag reads done
    int wb = srow * LDK + ssub;
    *(v8h*)&Ah[wb]     = ah0;
    *(v8h*)&Ah[wb + 8] = ah1;
    *(v8h*)&Al[wb]     = al0;
    *(v8h*)&Al[wb + 8] = al1;
    *(v8h*)&Bh[wb]     = bh0;
    *(v8h*)&Bh[wb + 8] = bh1;
    *(v8h*)&Bl[wb]     = bl0;
    *(v8h*)&Bl[wb + 8] = bl1;
    __syncthreads();

    v8h fah[4], fal[4];
#pragma unroll
    for (int m = 0; m < 4; ++m) {
      int row = wr * 64 + m * 16 + lr;
      fah[m] = *(const v8h*)&Ah[row * LDK + k8];
      fal[m] = *(const v8h*)&Al[row * LDK + k8];
    }
#pragma unroll
    for (int n = 0; n < 4; ++n) {
      int col = wc * 64 + n * 16 + lr;
      v8h fbh = *(const v8h*)&Bh[col * LDK + k8];
      v8h fbl = *(const v8h*)&Bl[col * LDK + k8];
#pragma unroll
      for (int m = 0; m < 4; ++m) {
        acc[m][n] = __builtin_amdgcn_mfma_f32_16x16x32_f16(fah[m], fbh, acc[m][n], 0, 0, 0);
        acc[m][n] = __builtin_amdgcn_mfma_f32_16x16x32_f16(fah[m], fbl, acc[m][n], 0, 0, 0);
        acc[m][n] = __builtin_amdgcn_mfma_f32_16x16x32_f16(fal[m], fbh, acc[m][n], 0, 0, 0);
      }
    }
  }

  float cnp[4];
#pragma unroll
  for (int n = 0; n < 4; ++n) cnp[n] = Bn[c0 + wc * 64 + n * 16 + lr];

#pragma unroll
  for (int m = 0; m < 4; ++m) {
    int rl = wr * 64 + m * 16 + (l >> 4) * 4;
#pragma unroll
    for (int r = 0; r < 4; ++r) {
      int org = idx[r0 + rl + r];
      float rq = An[r0 + rl + r];
      float* sp = S + (size_t)org * KC + c0;
#pragma unroll
      for (int n = 0; n < 4; ++n) {
        int cl = wc * 64 + n * 16 + lr;
        sp[cl] = -((rq + cnp[n]) - 2.0f * acc[m][n][r]);
      }
    }
  }
}

// ---------------- pad rows: counts(c0=10), qout zeros, loss += x^2 ----------------
__global__ __launch_bounds__(256) void k_pad(const float* __restrict__ X,
                                             const int* __restrict__ idx,
                                             const int* __restrict__ npp,
                                             float* __restrict__ qout,
                                             float* __restrict__ sout,
                                             double* __restrict__ esum) {
  int NP = *npp;
  int slot = blockIdx.x * 4 + (threadIdx.x >> 6);
  if (slot < NP) return;   // wave-uniform exit (non-pad handled by sampler)
  int n = idx[slot];
  int l = threadIdx.x & 63;

  float* so = sout + (size_t)n * KC + l * 16;
  float4 z = make_float4(0.f, 0.f, 0.f, 0.f);
  *(float4*)(so)      = (l == 0) ? make_float4(10.f, 0.f, 0.f, 0.f) : z;
  *(float4*)(so + 4)  = z;
  *(float4*)(so + 8)  = z;
  *(float4*)(so + 12) = z;

  const float* xr = X + (size_t)n * DM + l * 8;
  float4 x0 = *(const float4*)xr, x1 = *(const float4*)(xr + 4);
  float* qo = qout + (size_t)n * DM + l * 8;
  *(float4*)qo       = z;
  *(float4*)(qo + 4) = z;
  double ls = (double)(x0.x*x0.x) + (double)(x0.y*x0.y)
            + (double)(x0.z*x0.z) + (double)(x0.w*x0.w)
            + (double)(x1.x*x1.x) + (double)(x1.y*x1.y)
            + (double)(x1.z*x1.z) + (double)(x1.w*x1.w);
#pragma unroll
  for (int off = 32; off; off >>= 1) ls += __shfl_xor(ls, off, 64);
  if (l == 0) atomicAdd(&esum[n & 63], ls);
}

// ---------------- sampling on compacted non-pad rows (R8 form, pure) ----------------
// Bit-identical draw stream: bits = o0^o1 of threefry(key,(0,t));
// argmax_k(g_k+l_k) == argmax_k fl(log2(u_k)*m_k), m_k = ln2*exp(lmax-l_k).
__global__ __launch_bounds__(256, 8) void k_sample_i(
    const float* __restrict__ S, const float* __restrict__ X,
    const float* __restrict__ CW, const int* __restrict__ idx,
    const int* __restrict__ npp,
    float* __restrict__ qout, float* __restrict__ sout,
    float* __restrict__ cnt, double* __restrict__ esum) {
  int NP = *npp;
  int slot = blockIdx.x * 4 + (threadIdx.x >> 6);
  if (slot >= NP) return;   // wave-uniform exit
  int n = idx[slot];
  int l = threadIdx.x & 63;
  int base = l * 16;
  const float* srow = S + (size_t)n * KC + base;

  // row max (transient lg regs)
  float lmax;
  {
    float lg0[16];
#pragma unroll
    for (int j = 0; j < 16; j += 4)
      *(float4*)&lg0[j] = *(const float4*)(srow + j);
    if (l == 0) lg0[0] = -__builtin_inff();
    lmax = lg0[0];
#pragma unroll
    for (int i = 1; i < 16; ++i) lmax = fmaxf(lmax, lg0[i]);
#pragma unroll
    for (int off = 32; off; off >>= 1)
      lmax = fmaxf(lmax, __shfl_xor(lmax, off, 64));
  }

  float bv[10];
  uint32_t bi[10];
#pragma unroll
  for (int s = 0; s < 10; ++s) { bv[s] = -__builtin_inff(); bi[s] = 0xFFFFFFFFu; }

  uint32_t tb0 = (uint32_t)n * (uint32_t)KC + (uint32_t)base;
#pragma unroll 1
  for (int j = 0; j < 16; ++j) {
    float lgj = srow[j];                 // L1-hot scalar reload
    uint32_t kk = (uint32_t)(base + j);
    if (kk == 0u) lgj = -__builtin_inff();  // code 0 disallowed
    float mj = 0.69314718056f * __expf(lmax - lgj);
    uint32_t t0 = tb0 + (uint32_t)j;
#pragma unroll
    for (int sp = 0; sp < 5; ++sp) {
      uint32_t ba, bb;
      threefry_x2(t0 + (uint32_t)(2 * sp) * NKPROD,
                  t0 + (uint32_t)(2 * sp + 1) * NKPROD, ba, bb);
      float fa = __uint_as_float((ba >> 9) | 0x3F800000u) - 1.0f;
      float fb = __uint_as_float((bb >> 9) | 0x3F800000u) - 1.0f;
      float ua = fmaxf(1.17549435e-38f, fa);
      float ub = fmaxf(1.17549435e-38f, fb);
      float va = __log2f(ua) * mj;
      float vb = __log2f(ub) * mj;
      if (va > bv[2 * sp])     { bv[2 * sp] = va;     bi[2 * sp] = kk; }
      if (vb > bv[2 * sp + 1]) { bv[2 * sp + 1] = vb; bi[2 * sp + 1] = kk; }
    }
  }

  // wave argmax per draw (first-index tiebreak)
#pragma unroll
  for (int s = 0; s < 10; ++s) {
#pragma unroll
    for (int off = 32; off; off >>= 1) {
      float ov = __shfl_xor(bv[s], off, 64);
      uint32_t oi = __shfl_xor(bi[s], off, 64);
      if (ov > bv[s] || (ov == bv[s] && oi < bi[s])) { bv[s] = ov; bi[s] = oi; }
    }
  }

  // counts (transient; overwrites this row's logits)
  float* so = sout + (size_t)n * KC + base;
#pragma unroll
  for (int j4 = 0; j4 < 16; j4 += 4) {
    float c[4];
#pragma unroll
    for (int i = 0; i < 4; ++i) {
      uint32_t k = (uint32_t)(base + j4 + i);
      float cc = 0.f;
#pragma unroll
      for (int s = 0; s < 10; ++s) cc += (bi[s] == k) ? 1.f : 0.f;
      c[i] = cc;
    }
    *(float4*)(so + j4) = make_float4(c[0], c[1], c[2], c[3]);
  }

  // quantized gather (bi wave-uniform; codebook L2-hot) + ST + loss
  float q[8];
#pragma unroll
  for (int i = 0; i < 8; ++i) q[i] = 0.f;
#pragma unroll
  for (int s = 0; s < 10; ++s) {
    const float* cr = CW + (size_t)bi[s] * DM + l * 8;
    float4 g0 = *(const float4*)cr;
    float4 g1 = *(const float4*)(cr + 4);
    q[0] += g0.x; q[1] += g0.y; q[2] += g0.z; q[3] += g0.w;
    q[4] += g1.x; q[5] += g1.y; q[6] += g1.z; q[7] += g1.w;
    if (l == 0) atomicAdd(&cnt[bi[s]], 1.0f);
  }

  const float* xr = X + (size_t)n * DM + l * 8;
  float4 x0 = *(const float4*)xr, x1 = *(const float4*)(xr + 4);
  float xs[8] = {x0.x, x0.y, x0.z, x0.w, x1.x, x1.y, x1.z, x1.w};
  float st[8];
  double ls = 0.0;
#pragma unroll
  for (int j = 0; j < 8; ++j) {
    float qq = q[j] / 10.0f;
    float d = qq - xs[j];
    ls += (double)(d * d);
    st[j] = xs[j] + d;
  }
  float* qo = qout + (size_t)n * DM + l * 8;
  *(float4*)qo       = make_float4(st[0], st[1], st[2], st[3]);
  *(float4*)(qo + 4) = make_float4(st[4], st[5], st[6], st[7]);

#pragma unroll
  for (int off = 32; off; off >>= 1) ls += __shfl_xor(ls, off, 64);
  if (l == 0) atomicAdd(&esum[n & 63], ls);   // 64 striped slots
}

// ---------------- scalars: loss + perplexity ----------------
__global__ __launch_bounds__(256) void k_final(const int* __restrict__ npp,
                                               const float* __restrict__ cnt,
                                               const double* __restrict__ esum,
                                               float* __restrict__ scal) {
  __shared__ double snd[256];
  int t = threadIdx.x;
  int npad = NROWS - *npp;
  double ss = 0.0;
  for (int k = t; k < KC; k += 256) {
    float c = (k == 0) ? (float)(npad * 10) : cnt[k];
    float p = c / 327680.0f;   // / (N * NUM_SAMPLES)
    ss += (double)(p * logf(p + 1e-10f));
  }
  snd[t] = ss;
  __syncthreads();
  for (int off = 128; off; off >>= 1) {
    if (t < off) snd[t] += snd[t + off];
    __syncthreads();
  }
  if (t == 0) {
    double es = 0.0;
    for (int i = 0; i < 64; ++i) es += esum[i];
    float num_nonpad = (float)((NROWS - npad) * DM);
    float el = (float)es / num_nonpad;
    scal[0] = 0.25f * el;               // loss
    scal[1] = expf(-(float)snd[0]);     // perplexity
  }
}

extern "C" void kernel_launch(void* const* d_in, const int* in_sizes, int n_in,
                              void* d_out, int out_size, void* d_ws, size_t ws_size,
                              hipStream_t stream) {
  const float* X  = (const float*)d_in[0];
  const void*  M  = d_in[1];
  const float* CW = (const float*)d_in[2];
  float* out  = (float*)d_out;
  float* qout = out;                    // [0, 16777216): quantized_st
  float* sout = out + 16777216;         // [.., 50331648): logits -> samples
  float* scal = out + 50331648;         // loss, perplexity
  // A pre-split (by compact slot) occupies the qout region EXACTLY
  // (32768*512*2B*2 = 67,108,864 B); every byte rewritten by pad/sampler.
  _Float16* Ah2 = (_Float16*)qout;
  _Float16* Al2 = Ah2 + 16777216;
  uint8_t* ws = (uint8_t*)d_ws;
  double*   esum = (double*)ws;           // 512 B (64 striped slots)
  uint32_t* flag = (uint32_t*)(ws + 512);
  int*      npp  = (int*)(ws + 768);
  float*    cnt  = (float*)(ws + 1024);   // 4 KB per-code totals
  int*      cntB = (int*)(ws + 5120);     // 256 B per-block counts (bool interp)
  int*      cntI = (int*)(ws + 5376);     // 256 B per-block counts (int interp)
  int*      idx  = (int*)(ws + 8192);     // 128 KB: nonpad [0,NP) + pad [NP,32768)
  float*    An   = (float*)(ws + 139264); // 128 KB: A row norms by slot
  _Float16* Bh2  = (_Float16*)(ws + 270336);          // 1 MiB
  _Float16* Bl2  = (_Float16*)(ws + 270336 + 1048576);// 1 MiB
  float*    Bn   = (float*)(ws + 270336 + 2097152);   // 4 KB
  (void)in_sizes; (void)n_in; (void)out_size; (void)ws_size;

  hipMemsetAsync(d_ws, 0, 8192, stream);   // esum + flag + npp + cnt
  k_count<<<64, 256, 0, stream>>>((const uint8_t*)M, flag, cntB, cntI);
  k_scatter<<<64, 256, 0, stream>>>((const uint8_t*)M, flag, cntB, cntI, idx, npp);
  k_asplit<<<8192, 256, 0, stream>>>(X, idx, Ah2, Al2, An);
  k_bsplit<<<256, 256, 0, stream>>>(CW, Bh2, Bl2, Bn);
  k_gemm5<<<2048, 256, 0, stream>>>(Ah2, Al2, An, Bh2, Bl2, Bn, idx, npp, sout);
  k_pad<<<8192, 256, 0, stream>>>(X, idx, npp, qout, sout, esum);
  k_sample_i<<<8192, 256, 0, stream>>>(sout, X, CW, idx, npp, qout, sout, cnt, esum);
  k_final<<<1, 256, 0, stream>>>(npp, cnt, esum, scal);
}